// Round 10
// baseline (457.448 us; speedup 1.0000x reference)
//
#include <hip/hip_runtime.h>
#include <hip/hip_bf16.h>

#define NN 50000
#define EE 800000
#define NE 850000       // edges + self-loops
#define HID 128
#define NEG_SLOPE 0.2f
#define EPSN 1e-5f
#define NB 196          // buckets of 256 nodes
#define BCAP 6144       // bucket capacity (expected 4352 +- 64)
#define TB 4096         // edges per k_bin block
#define REP 32          // GraphNorm stats replicas (per-layer region)
#define NPB 8           // nodes per k_gat_node block (4 per wave, 2 waves)
#define GCAP 512        // staged csr offsets per gat block (mean 136)
#define LOG2E 1.4426950408889634f

typedef __attribute__((ext_vector_type(8))) short bf16x8;
typedef __attribute__((ext_vector_type(4))) float f32x4;
typedef __attribute__((ext_vector_type(2))) float f32x2;

__device__ __forceinline__ unsigned short f2b(float f) {
    unsigned u = __float_as_uint(f);
    unsigned r = (u + 0x7FFFu + ((u >> 16) & 1u)) >> 16;
    return (unsigned short)r;
}
__device__ __forceinline__ float b2f(unsigned short u) {
    return __uint_as_float(((unsigned)u) << 16);
}
__device__ __forceinline__ float2 up2(unsigned u) {
    return make_float2(__uint_as_float(u << 16),
                       __uint_as_float(u & 0xFFFF0000u));
}
// packed-f32 (VOP3P) helpers — clang won't form these from scalar code
__device__ __forceinline__ f32x2 up2p(unsigned u) {
    f32x2 r;
    r[0] = __uint_as_float(u << 16);
    r[1] = __uint_as_float(u & 0xFFFF0000u);
    return r;
}
__device__ __forceinline__ f32x2 pka(f32x2 a, f32x2 b) {
    f32x2 d;
    asm("v_pk_add_f32 %0, %1, %2" : "=v"(d) : "v"(a), "v"(b));
    return d;
}
__device__ __forceinline__ f32x2 pkm(f32x2 a, f32x2 b) {
    f32x2 d;
    asm("v_pk_mul_f32 %0, %1, %2" : "=v"(d) : "v"(a), "v"(b));
    return d;
}
__device__ __forceinline__ f32x2 pkf(f32x2 a, f32x2 b, f32x2 c) {
    f32x2 d;
    asm("v_pk_fma_f32 %0, %1, %2, %3" : "=v"(d) : "v"(a), "v"(b), "v"(c));
    return d;
}
__device__ __forceinline__ f32x2 pabs2(f32x2 v) {
    f32x2 r;
    r[0] = __builtin_fabsf(v[0]);
    r[1] = __builtin_fabsf(v[1]);
    return r;
}
// quad_perm DPP add (4-lane head-group reduce)
#define QPADD(p, CTRL)                                                         \
    __int_as_float(__builtin_amdgcn_update_dpp(                                \
        __float_as_int(p), __float_as_int(p), CTRL, 0xF, 0xF, false))

// Fragment-linear weight layout: [ct][ks][quad][l16][8] — 64 lanes of a wave
// read one contiguous 1KB block per B-operand load (fully coalesced).

// ---------------- prep: W->bf16 frag-linear, x->bf16, zero bcnt + stats ------
__global__ void k_prep(const float* __restrict__ x, const float* __restrict__ Wl,
                       const float* __restrict__ Wr, const float* __restrict__ skip_W,
                       unsigned short* __restrict__ xb, unsigned short* __restrict__ wt,
                       unsigned short* __restrict__ st, int* __restrict__ bcnt,
                       float* __restrict__ stats) {
    int i = blockIdx.x * blockDim.x + threadIdx.x;
    if (i < NN * HID / 4) {
        float4 v = *(const float4*)&x[i * 4];
        ushort4 o = {f2b(v.x), f2b(v.y), f2b(v.z), f2b(v.w)};
        *(ushort4*)&xb[i * 4] = o;
    }
    if (i < NB) bcnt[i] = 0;
    if (i < 4 * REP * 256) stats[i] = 0.f;      // 4 per-layer regions
    if (i < 4 * 256 * 128) {
        int l = i >> 15, idx = i & 32767;
        int j = idx & 7;
        int l16 = (idx >> 3) & 15;
        int quad = (idx >> 7) & 3;
        int ks = (idx >> 9) & 3;
        int ct = idx >> 11;            // 0..15
        int c = ct * 16 + l16;         // output col 0..255
        int k = quad * 8 + ks * 32 + j;// input dim 0..127
        float v = (c < 128) ? Wl[l * 16384 + k * 128 + c]
                            : Wr[l * 16384 + k * 128 + (c - 128)];
        wt[i] = f2b(v);
    } else if (i < 4 * 256 * 128 + 128 * 128) {
        int idx = i - 4 * 256 * 128;   // 0..16383
        int j = idx & 7;
        int l16 = (idx >> 3) & 15;
        int quad = (idx >> 7) & 3;
        int ks = (idx >> 9) & 3;
        int ct = idx >> 11;            // 0..7
        int c = ct * 16 + l16;         // output col 0..127
        int k = quad * 8 + ks * 32 + j;
        st[idx] = f2b(skip_W[k * 128 + c]);
    }
}

// ---------------- CSR build: bucket sort ----------------
__global__ void __launch_bounds__(256) k_bin(const int* __restrict__ ei,
                                             int* __restrict__ bcnt,
                                             unsigned* __restrict__ bbuf) {
    __shared__ int hist[NB];
    __shared__ int gbase[NB];
    int t = threadIdx.x;
    for (int b = t; b < NB; b += 256) hist[b] = 0;
    __syncthreads();
    int e0 = blockIdx.x * TB;
    unsigned ent[16];
    int bkt[16];
#pragma unroll
    for (int k = 0; k < 16; k++) {
        int e = e0 + k * 256 + t;
        if (e < NE) {
            int src, dst;
            if (e < EE) { src = ei[e]; dst = ei[EE + e]; }
            else        { src = e - EE; dst = src; }
            int b = dst >> 8;
            ent[k] = ((unsigned)(dst & 255) << 17) | (unsigned)src;
            bkt[k] = b;
            atomicAdd(&hist[b], 1);
        } else bkt[k] = -1;
    }
    __syncthreads();
    for (int b = t; b < NB; b += 256) {
        int c = hist[b];
        gbase[b] = (c > 0) ? atomicAdd(&bcnt[b], c) : 0;
        hist[b] = 0;
    }
    __syncthreads();
#pragma unroll
    for (int k = 0; k < 16; k++) {
        int b = bkt[k];
        if (b >= 0) {
            int pos = gbase[b] + atomicAdd(&hist[b], 1);
            if (pos < BCAP) bbuf[(size_t)b * BCAP + pos] = ent[k];
        }
    }
}

// Per-bucket CSR with inline prefix scan; csr stores BYTE offsets (src*512).
__global__ void __launch_bounds__(256) k_bucket_csr(
    const unsigned* __restrict__ bbuf, const int* __restrict__ bcnt,
    int* __restrict__ row_ptr, int* __restrict__ csr_off) {
    __shared__ unsigned se[BCAP];
    __shared__ int pre[256];
    __shared__ int hist[256], scn[256], exs[256], cur[256];
    int b = blockIdx.x, t = threadIdx.x;
    int bv = (t < NB) ? bcnt[t] : 0;
    pre[t] = bv;
    __syncthreads();
    for (int o = 1; o < 256; o <<= 1) {
        int u = (t >= o) ? pre[t - o] : 0;
        __syncthreads();
        pre[t] += u;
        __syncthreads();
    }
    int cntb = bcnt[b];
    int base = pre[b] - cntb;          // exclusive prefix
    int cnt = min(cntb, BCAP);
    hist[t] = 0;
    cur[t] = 0;
    __syncthreads();
    for (int j = t; j < cnt; j += 256) {
        unsigned e = bbuf[(size_t)b * BCAP + j];
        se[j] = e;
        atomicAdd(&hist[e >> 17], 1);
    }
    __syncthreads();
    int v = hist[t];
    scn[t] = v;
    __syncthreads();
    for (int o = 1; o < 256; o <<= 1) {
        int u = (t >= o) ? scn[t - o] : 0;
        __syncthreads();
        scn[t] += u;
        __syncthreads();
    }
    int ex = scn[t] - v;
    exs[t] = ex;
    int node = b * 256 + t;
    if (node < NN) row_ptr[node] = base + ex;
    if (b == NB - 1 && t == 0) row_ptr[NN] = NE;
    __syncthreads();
    for (int j = t; j < cnt; j += 256) {
        unsigned e = se[j];
        int dl = e >> 17;
        int p = exs[dl] + atomicAdd(&cur[dl], 1);
        csr_off[base + p] = (int)((e & 0x1FFFFu) << 9);   // src * 512 bytes
    }
}

// ---------------- MFMA GEMM (layer 0 only), column-split x2 ----------------
// grid = rtiles*2: blockIdx>>1 = row tile, &1 = col half (8 of 16 ct tiles).
// Doubles resident waves on this grid-capped latency-bound kernel.
__global__ void __launch_bounds__(256) k_gemm_dual_mfma(
    const unsigned short* __restrict__ Xb, const unsigned short* __restrict__ WT,
    unsigned short* __restrict__ C) {
    int t = threadIdx.x;
    int rt = blockIdx.x >> 1, ch = blockIdx.x & 1;
    int w = t >> 6, lane = t & 63;
    int quad = lane >> 4, l16 = lane & 15;
    int r0 = rt * 64 + w * 16;
    int lrow = r0 + l16; if (lrow >= NN) lrow = NN - 1;
    const unsigned short* arow = Xb + (size_t)lrow * 128 + quad * 8;
    bf16x8 a[4];
#pragma unroll
    for (int ks = 0; ks < 4; ks++) a[ks] = *(const bf16x8*)(arow + ks * 32);
    const unsigned short* wbase = WT + ch * 16384 + quad * 128 + l16 * 8;
    f32x4 acc[8];
#pragma unroll
    for (int ct = 0; ct < 8; ct++) acc[ct] = (f32x4){0, 0, 0, 0};
#pragma unroll
    for (int ct = 0; ct < 8; ct++) {
#pragma unroll
        for (int ks = 0; ks < 4; ks++) {
            bf16x8 b = *(const bf16x8*)(wbase + ct * 2048 + ks * 512);
            acc[ct] = __builtin_amdgcn_mfma_f32_16x16x32_bf16(a[ks], b, acc[ct], 0, 0, 0);
        }
    }
    int sr = r0 + quad * 4;
#pragma unroll
    for (int ct = 0; ct < 8; ct++) {
#pragma unroll
        for (int r = 0; r < 4; r++) {
            int rr = sr + r;
            if (rr < NN) C[(size_t)rr * 256 + ch * 128 + ct * 16 + l16] = f2b(acc[ct][r]);
        }
    }
}

// ---------------- per-block GraphNorm scoff reduce (replaces k_finalize) ----
__device__ __forceinline__ void scoff_reduce(
    const float* __restrict__ stats_l, const float* __restrict__ gn_w,
    const float* __restrict__ gn_b, const float* __restrict__ gn_ms,
    int t, float* s_tot, float* s_sc) {
    float ssum = 0.f;
    const float* sp = stats_l + t;
#pragma unroll
    for (int r = 0; r < REP; r++) ssum += sp[r * 256];
    s_tot[t] = ssum;
    __syncthreads();
    if (t < 128) {
        const float invN = 1.0f / (float)NN;
        float mean = s_tot[t] * invN;
        float ex2 = s_tot[128 + t] * invN;
        float ms = gn_ms[t];
        float var = ex2 - (2.f * ms - ms * ms) * mean * mean;
        float wsc = gn_w[t] * rsqrtf(var + EPSN);
        s_sc[t] = wsc;
        s_sc[128 + t] = gn_b[t] - wsc * ms * mean;
    }
    __syncthreads();
}

// ---------------- skip-GEMM core: acc[8] = ELU(scale*h+off) @ skipW ----------------
__device__ __forceinline__ void skip_core(
    const unsigned short* __restrict__ hbufb, const float* scoff,
    const unsigned short* __restrict__ ST, int lrow, int quad, int l16,
    f32x4 (&acc)[8]) {
    const unsigned short* hrow = hbufb + (size_t)lrow * 128 + quad * 8;
    const unsigned short* stbase = ST + quad * 128 + l16 * 8;   // frag-linear
#pragma unroll
    for (int ct = 0; ct < 8; ct++) acc[ct] = (f32x4){0, 0, 0, 0};
#pragma unroll
    for (int ks = 0; ks < 4; ks++) {
        int k0 = ks * 32;
        int kc = quad * 8 + k0;
        uint4 hw = *(const uint4*)(hrow + k0);
        float2 h01 = up2(hw.x), h23 = up2(hw.y), h45 = up2(hw.z), h67 = up2(hw.w);
        float4 sc0 = *(const float4*)(scoff + kc);
        float4 sc1 = *(const float4*)(scoff + kc + 4);
        float4 of0 = *(const float4*)(scoff + 128 + kc);
        float4 of1 = *(const float4*)(scoff + 128 + kc + 4);
        float e[8];
        e[0] = fmaf(sc0.x, h01.x, of0.x); e[1] = fmaf(sc0.y, h01.y, of0.y);
        e[2] = fmaf(sc0.z, h23.x, of0.z); e[3] = fmaf(sc0.w, h23.y, of0.w);
        e[4] = fmaf(sc1.x, h45.x, of1.x); e[5] = fmaf(sc1.y, h45.y, of1.y);
        e[6] = fmaf(sc1.z, h67.x, of1.z); e[7] = fmaf(sc1.w, h67.y, of1.w);
        bf16x8 af;
#pragma unroll
        for (int j = 0; j < 8; j++) {
            float v = e[j];
            v = (v > 0.f) ? v : (__expf(v) - 1.f);
            af[j] = (short)f2b(v);
        }
#pragma unroll
        for (int ct = 0; ct < 8; ct++) {
            bf16x8 b = *(const bf16x8*)(stbase + ct * 2048 + ks * 512);
            acc[ct] = __builtin_amdgcn_mfma_f32_16x16x32_bf16(af, b, acc[ct], 0, 0, 0);
        }
    }
}

// ---------------- fused scoff + skip + next-layer dual GEMM, col-split x2 ----
// grid = rtiles*2. Both col-halves stage oldX (from the READ buffer) and
// compute skip+residual identically in LDS; only ch==0 writes the new
// residual stream (to the WRITE buffer — ping-pong across layers removes the
// read/write race between col-halves); each half computes 8 of 16 ct tiles
// of the next-layer dual GEMM (dacc 8 not 16 -> lower VGPR, 2x waves).
__global__ void __launch_bounds__(256) k_skip_dual(
    const unsigned short* __restrict__ hbufb, const float* __restrict__ stats_l,
    const float* __restrict__ gn_w, const float* __restrict__ gn_b,
    const float* __restrict__ gn_ms,
    const unsigned short* __restrict__ ST, const float* __restrict__ skip_b,
    const unsigned short* __restrict__ Xbr, unsigned short* __restrict__ Xbw,
    const unsigned short* __restrict__ WTnext, unsigned short* __restrict__ xlr) {
    __shared__ unsigned short tileX[64][136];      // block-wide new X (bf16)
    __shared__ unsigned short tileC[4][16][136];   // per-wave xlr half staging
    __shared__ __align__(16) float s_tot[256];
    __shared__ __align__(16) float s_sc[256];
    int t = threadIdx.x;
    int rt = blockIdx.x >> 1, ch = blockIdx.x & 1;
    int w = t >> 6, lane = t & 63;
    int quad = lane >> 4, l16 = lane & 15;
    int r0b = rt * 64;
    int r0 = r0b + w * 16;
    int lrow = r0 + l16; if (lrow >= NN) lrow = NN - 1;
#pragma unroll
    for (int it = 0; it < 4; it++) {
        int idx = it * 256 + t;
        int row = idx >> 4;
        int c8 = (idx & 15) * 8;
        int rr = r0b + row;
        uint4 v = (rr < NN) ? *(const uint4*)&Xbr[(size_t)rr * 128 + c8]
                            : (uint4){0, 0, 0, 0};
        *(uint4*)&tileX[row][c8] = v;
    }
    scoff_reduce(stats_l, gn_w, gn_b, gn_ms, t, s_tot, s_sc);
    f32x4 acc[8];
    skip_core(hbufb, s_sc, ST, lrow, quad, l16, acc);
    __syncthreads();
#pragma unroll
    for (int ct = 0; ct < 8; ct++) {
        int c = ct * 16 + l16;
        float sb = skip_b[c];
#pragma unroll
        for (int r = 0; r < 4; r++) {
            int wrow = w * 16 + quad * 4 + r;
            float v = b2f(tileX[wrow][c]) + acc[ct][r] + sb;
            tileX[wrow][c] = f2b(v);
        }
    }
    __syncthreads();
    if (ch == 0) {
#pragma unroll
        for (int it = 0; it < 4; it++) {
            int idx = it * 256 + t;
            int row = idx >> 4;
            int c8 = (idx & 15) * 8;
            int rr = r0b + row;
            if (rr < NN) *(uint4*)&Xbw[(size_t)rr * 128 + c8] = *(const uint4*)&tileX[row][c8];
        }
    }
    int wrowA = w * 16 + l16;
    bf16x8 a[4];
#pragma unroll
    for (int ks = 0; ks < 4; ks++)
        a[ks] = *(const bf16x8*)&tileX[wrowA][quad * 8 + ks * 32];
    const unsigned short* wbase = WTnext + ch * 16384 + quad * 128 + l16 * 8;
    f32x4 dacc[8];
#pragma unroll
    for (int ct = 0; ct < 8; ct++) dacc[ct] = (f32x4){0, 0, 0, 0};
#pragma unroll
    for (int ct = 0; ct < 8; ct++) {
#pragma unroll
        for (int ks = 0; ks < 4; ks++) {
            bf16x8 b = *(const bf16x8*)(wbase + ct * 2048 + ks * 512);
            dacc[ct] = __builtin_amdgcn_mfma_f32_16x16x32_bf16(a[ks], b, dacc[ct], 0, 0, 0);
        }
    }
#pragma unroll
    for (int ct = 0; ct < 8; ct++) {
#pragma unroll
        for (int r = 0; r < 4; r++)
            tileC[w][quad * 4 + r][ct * 16 + l16] = f2b(dacc[ct][r]);
    }
    __syncthreads();
#pragma unroll
    for (int it = 0; it < 4; it++) {
        int idx = it * 64 + lane;
        int row = idx >> 4;
        int c8 = (idx & 15) * 8;
        int rr = r0 + row;
        if (rr < NN)
            *(uint4*)&xlr[(size_t)rr * 256 + ch * 128 + c8] =
                *(const uint4*)&tileC[w][row][c8];
    }
}

// ---------------- fused scoff + skip + final fc (last layer) ----------------
__global__ void __launch_bounds__(256) k_skip_fc(
    const unsigned short* __restrict__ hbufb, const float* __restrict__ stats_l,
    const float* __restrict__ gn_w, const float* __restrict__ gn_b,
    const float* __restrict__ gn_ms,
    const unsigned short* __restrict__ ST, const float* __restrict__ skip_b,
    const unsigned short* __restrict__ Xbr,
    const float* __restrict__ fc_W, const float* __restrict__ fc_b,
    float* __restrict__ out) {
    __shared__ unsigned short tileX[64][136];
    __shared__ __align__(16) float s_tot[256];
    __shared__ __align__(16) float s_sc[256];
    int t = threadIdx.x;
    int w = t >> 6, lane = t & 63;
    int quad = lane >> 4, l16 = lane & 15;
    int r0b = blockIdx.x * 64;
    int r0 = r0b + w * 16;
    int lrow = r0 + l16; if (lrow >= NN) lrow = NN - 1;
#pragma unroll
    for (int it = 0; it < 4; it++) {
        int idx = it * 256 + t;
        int row = idx >> 4;
        int c8 = (idx & 15) * 8;
        int rr = r0b + row;
        uint4 v = (rr < NN) ? *(const uint4*)&Xbr[(size_t)rr * 128 + c8]
                            : (uint4){0, 0, 0, 0};
        *(uint4*)&tileX[row][c8] = v;
    }
    scoff_reduce(stats_l, gn_w, gn_b, gn_ms, t, s_tot, s_sc);
    f32x4 acc[8];
    skip_core(hbufb, s_sc, ST, lrow, quad, l16, acc);
    __syncthreads();
    float p[4] = {0.f, 0.f, 0.f, 0.f};
#pragma unroll
    for (int ct = 0; ct < 8; ct++) {
        int c = ct * 16 + l16;
        float sb = skip_b[c];
        float fw = fc_W[c];
#pragma unroll
        for (int r = 0; r < 4; r++) {
            int wrow = w * 16 + quad * 4 + r;
            float v = b2f(tileX[wrow][c]) + acc[ct][r] + sb;
            p[r] = fmaf(v, fw, p[r]);
        }
    }
#pragma unroll
    for (int r = 0; r < 4; r++) {
        p[r] += __shfl_xor(p[r], 1);
        p[r] += __shfl_xor(p[r], 2);
        p[r] += __shfl_xor(p[r], 4);
        p[r] += __shfl_xor(p[r], 8);
    }
    if (l16 == 0) {
        float fb = fc_b[0];
#pragma unroll
        for (int r = 0; r < 4; r++) {
            int rr = r0 + quad * 4 + r;
            if (rr < NN) out[rr] = p[r] + fb;
        }
    }
}

// ---------------- GAT edge step ----------------
__device__ __forceinline__ void proc_edge(
    const uint4& xw, const f32x2* xr2, const f32x2* at06, const f32x2* at04,
    float& den, f32x2* acc) {
    f32x2 f0 = up2p(xw.x), f1 = up2p(xw.y);
    f32x2 f2v = up2p(xw.z), f3 = up2p(xw.w);
    f32x2 s0 = pka(f0, xr2[0]);
    f32x2 s1 = pka(f1, xr2[1]);
    f32x2 s2 = pka(f2v, xr2[2]);
    f32x2 s3 = pka(f3, xr2[3]);
    // two 4-deep chains instead of one 8-deep
    f32x2 ps1 = pkm(at06[0], s0);
    ps1 = pkf(at04[0], pabs2(s0), ps1);
    ps1 = pkf(at06[1], s1, ps1);
    ps1 = pkf(at04[1], pabs2(s1), ps1);
    f32x2 ps2 = pkm(at06[2], s2);
    ps2 = pkf(at04[2], pabs2(s2), ps2);
    ps2 = pkf(at06[3], s3, ps2);
    ps2 = pkf(at04[3], pabs2(s3), ps2);
    float p = (ps1[0] + ps2[0]) + (ps1[1] + ps2[1]);
    p += QPADD(p, 0xB1);     // xor 1 within quad (head group)
    p += QPADD(p, 0x4E);     // xor 2 within quad
    float w = exp2f(p);
    den += w;
    f32x2 w2; w2[0] = w; w2[1] = w;
    acc[0] = pkf(w2, f0, acc[0]);
    acc[1] = pkf(w2, f1, acc[1]);
    acc[2] = pkf(w2, f2v, acc[2]);
    acc[3] = pkf(w2, f3, acc[3]);
}

// ---------------- fused GATv2: R7 proven structure (48 VGPR, 53 us floor) ----
// 128 threads = 2 waves; each wave owns 4 nodes (4 slots x 16 lanes; slot g
// takes edges == g mod 4). While-loop with register rotation, depth-4
// prefetch. Cross-slot reduce = in-wave butterfly; zero barriers in the main
// loop; LDS = 2KB.
__global__ void __launch_bounds__(128) k_gat_node(
    const unsigned short* __restrict__ xlr,
    const float* __restrict__ att, const float* __restrict__ conv_b,
    const int* __restrict__ row_ptr, const int* __restrict__ csr_off,
    unsigned short* __restrict__ houtb, float* __restrict__ stats_l) {
    __shared__ int s_off[GCAP];
    int t = threadIdx.x;
    int wv = t >> 6, lane = t & 63;
    int g = lane >> 4;       // slot 0..3 (within wave)
    int l = lane & 15;       // lane in slot: owns channels 8l..8l+7
    int i0 = blockIdx.x * NPB;
    int e0 = row_ptr[i0];
    int cnt = row_ptr[i0 + NPB] - e0;
    int stged = min(cnt, GCAP);
    for (int k = t; k < stged; k += 128) s_off[k] = csr_off[e0 + k];
    int n0 = i0 + wv * 4;    // this wave's first node
    int rp[5];
#pragma unroll
    for (int k = 0; k <= 4; k++) rp[k] = row_ptr[n0 + k];
    __syncthreads();

    const char* xbytes = (const char*)xlr;
    int lofs = 16 * l;
    f32x2 at06[4], at04[4];
    {
        float4 a0 = *(const float4*)&att[8 * l];
        float4 a1 = *(const float4*)&att[8 * l + 4];
        const float c6 = 0.6f * LOG2E, c4 = 0.4f * LOG2E;
        at06[0][0] = a0.x * c6; at06[0][1] = a0.y * c6;
        at06[1][0] = a0.z * c6; at06[1][1] = a0.w * c6;
        at06[2][0] = a1.x * c6; at06[2][1] = a1.y * c6;
        at06[3][0] = a1.z * c6; at06[3][1] = a1.w * c6;
        at04[0][0] = a0.x * c4; at04[0][1] = a0.y * c4;
        at04[1][0] = a0.z * c4; at04[1][1] = a0.w * c4;
        at04[2][0] = a1.x * c4; at04[2][1] = a1.y * c4;
        at04[3][0] = a1.z * c4; at04[3][1] = a1.w * c4;
    }
    int c0p = 8 * l + 2 * g;               // post-butterfly channel pair
    float2 cbp = *(const float2*)&conv_b[c0p];
    float saA = 0.f, sqA = 0.f, saB = 0.f, sqB = 0.f;

    // prologue: node 0 head state (depth-4: 3 heads in flight)
    uint4 xr_raw = *(const uint4*)(xbytes + (size_t)n0 * 512 + 256 + lofs);
    int start = rp[0] - e0, end = rp[1] - e0;
    int j = start + g;
    bool v0 = j < end;
    bool v1 = (j + 4) < end;
    bool v2 = (j + 8) < end;
    uint4 xw0 = {0, 0, 0, 0}, xw1 = {0, 0, 0, 0}, xw2 = {0, 0, 0, 0};
    if (v0) { int o = (j < stged) ? s_off[j] : csr_off[e0 + j];
              xw0 = *(const uint4*)(xbytes + (size_t)(unsigned)o + lofs); }
    if (v1) { int o = (j + 4 < stged) ? s_off[j + 4] : csr_off[e0 + j + 4];
              xw1 = *(const uint4*)(xbytes + (size_t)(unsigned)o + lofs); }
    if (v2) { int o = (j + 8 < stged) ? s_off[j + 8] : csr_off[e0 + j + 8];
              xw2 = *(const uint4*)(xbytes + (size_t)(unsigned)o + lofs); }

    for (int nn = 0; nn < 4; nn++) {
        f32x2 xr2[4];
        xr2[0] = up2p(xr_raw.x); xr2[1] = up2p(xr_raw.y);
        xr2[2] = up2p(xr_raw.z); xr2[3] = up2p(xr_raw.w);
        float den = 0.f;
        f32x2 acc[4];
#pragma unroll
        for (int k = 0; k < 4; k++) { acc[k][0] = 0.f; acc[k][1] = 0.f; }
        while (v0) {
            bool v3 = (j + 12) < end;
            uint4 xw3 = {0, 0, 0, 0};
            if (v3) { int o = (j + 12 < stged) ? s_off[j + 12] : csr_off[e0 + j + 12];
                      xw3 = *(const uint4*)(xbytes + (size_t)(unsigned)o + lofs); }
            proc_edge(xw0, xr2, at06, at04, den, acc);
            j += 4;
            v0 = v1; v1 = v2; v2 = v3;
            xw0 = xw1; xw1 = xw2; xw2 = xw3;
        }
        // save reduce inputs before clobbering pipeline state
        float r0v = acc[0][0], r1v = acc[0][1], r2v = acc[1][0], r3v = acc[1][1];
        float r4v = acc[2][0], r5v = acc[2][1], r6v = acc[3][0], r7v = acc[3][1];
        float dn = den;
        // issue next node's head prefetch BEFORE the reduce (hide latency)
        if (nn < 3) {
            xr_raw = *(const uint4*)(xbytes + (size_t)(n0 + nn + 1) * 512 + 256 + lofs);
            start = rp[nn + 1] - e0; end = rp[nn + 2] - e0;
            j = start + g;
            v0 = j < end;
            v1 = (j + 4) < end;
            v2 = (j + 8) < end;
            xw0 = (uint4){0, 0, 0, 0}; xw1 = (uint4){0, 0, 0, 0};
            xw2 = (uint4){0, 0, 0, 0};
            if (v0) { int o = (j < stged) ? s_off[j] : csr_off[e0 + j];
                      xw0 = *(const uint4*)(xbytes + (size_t)(unsigned)o + lofs); }
            if (v1) { int o = (j + 4 < stged) ? s_off[j + 4] : csr_off[e0 + j + 4];
                      xw1 = *(const uint4*)(xbytes + (size_t)(unsigned)o + lofs); }
            if (v2) { int o = (j + 8 < stged) ? s_off[j + 8] : csr_off[e0 + j + 8];
                      xw2 = *(const uint4*)(xbytes + (size_t)(unsigned)o + lofs); }
        }
        // cross-slot butterfly (slots = 16-lane groups): result in ALL lanes
        r0v += __shfl_xor(r0v, 16); r0v += __shfl_xor(r0v, 32);
        r1v += __shfl_xor(r1v, 16); r1v += __shfl_xor(r1v, 32);
        r2v += __shfl_xor(r2v, 16); r2v += __shfl_xor(r2v, 32);
        r3v += __shfl_xor(r3v, 16); r3v += __shfl_xor(r3v, 32);
        r4v += __shfl_xor(r4v, 16); r4v += __shfl_xor(r4v, 32);
        r5v += __shfl_xor(r5v, 16); r5v += __shfl_xor(r5v, 32);
        r6v += __shfl_xor(r6v, 16); r6v += __shfl_xor(r6v, 32);
        r7v += __shfl_xor(r7v, 16); r7v += __shfl_xor(r7v, 32);
        dn  += __shfl_xor(dn, 16);  dn  += __shfl_xor(dn, 32);
        // slot g finalizes channel pair 8l+2g (scalar ternaries: no arrays)
        float rA = (g == 0) ? r0v : (g == 1) ? r2v : (g == 2) ? r4v : r6v;
        float rB = (g == 0) ? r1v : (g == 1) ? r3v : (g == 2) ? r5v : r7v;
        float invd = 1.0f / dn;
        float hA = fmaf(rA, invd, cbp.x);
        float hB = fmaf(rB, invd, cbp.y);
        unsigned pkv = (unsigned)f2b(hA) | ((unsigned)f2b(hB) << 16);
        *(unsigned*)&houtb[(size_t)(n0 + nn) * 128 + c0p] = pkv;
        saA += hA; sqA += hA * hA;
        saB += hB; sqB += hB * hB;
    }
    {
        float* srep = stats_l + (size_t)(blockIdx.x & (REP - 1)) * 256;
        atomicAdd(&srep[c0p], saA);
        atomicAdd(&srep[c0p + 1], saB);
        atomicAdd(&srep[128 + c0p], sqA);
        atomicAdd(&srep[128 + c0p + 1], sqB);
    }
}

extern "C" void kernel_launch(void* const* d_in, const int* in_sizes, int n_in,
                              void* d_out, int out_size, void* d_ws, size_t ws_size,
                              hipStream_t stream) {
    const float* x_in   = (const float*)d_in[0];
    const int*   ei     = (const int*)d_in[1];
    const float* Wl     = (const float*)d_in[2];
    const float* Wr     = (const float*)d_in[3];
    const float* att    = (const float*)d_in[4];
    const float* conv_b = (const float*)d_in[5];
    const float* gn_w   = (const float*)d_in[6];
    const float* gn_b   = (const float*)d_in[7];
    const float* gn_ms  = (const float*)d_in[8];
    const float* skip_W = (const float*)d_in[9];
    const float* skip_b = (const float*)d_in[10];
    const float* fc_W   = (const float*)d_in[11];
    const float* fc_b   = (const float*)d_in[12];
    float* out = (float*)d_out;

    // workspace carve
    float* ws = (float*)d_ws;
    float* stats = ws;                              // 4 * REP * 256 (per-layer)
    unsigned short* xlr   = (unsigned short*)(stats + 4 * REP * 256); // N*256 bf16
    unsigned short* b16X0 = xlr + (size_t)NN * 256; // N*HID bf16 (residual ping)
    unsigned short* b16X1 = b16X0 + NN * HID;       // N*HID bf16 (residual pong)
    unsigned short* hbufb = b16X1 + NN * HID;       // N*HID bf16
    unsigned short* wt    = hbufb + NN * HID;       // 4*256*128 (frag-linear)
    unsigned short* st    = wt + 4 * 256 * 128;     // 128*128 (frag-linear)
    int* row_ptr = (int*)(st + 128 * 128);          // N+1
    int* bcnt    = row_ptr + NN + 1;                // NB
    int* csr_off = bcnt + NB;                       // NE (byte offsets)
    unsigned* bbuf = (unsigned*)(csr_off + NE);     // NB*BCAP

    k_prep<<<(NN * HID / 4 + 255) / 256, 256, 0, stream>>>(
        x_in, Wl, Wr, skip_W, b16X0, wt, st, bcnt, stats);

    // CSR build via bucket sort
    k_bin<<<(NE + TB - 1) / TB, 256, 0, stream>>>(ei, bcnt, bbuf);
    k_bucket_csr<<<NB, 256, 0, stream>>>(bbuf, bcnt, row_ptr, csr_off);

    const int rtiles = (NN + 63) / 64;              // 782
    const int gat_blocks = (NN + NPB - 1) / NPB;    // 6250
    k_gemm_dual_mfma<<<rtiles * 2, 256, 0, stream>>>(b16X0, wt, xlr);
    unsigned short* xbufs[2] = {b16X0, b16X1};
    for (int l = 0; l < 4; l++) {
        float* stats_l = stats + (size_t)l * REP * 256;
        k_gat_node<<<gat_blocks, 128, 0, stream>>>(
            xlr, att + l * HID, conv_b + l * HID, row_ptr, csr_off,
            hbufb, stats_l);
        if (l < 3) {
            k_skip_dual<<<rtiles * 2, 256, 0, stream>>>(
                hbufb, stats_l, gn_w + l * HID, gn_b + l * HID, gn_ms + l * HID,
                st, skip_b, xbufs[l & 1], xbufs[(l + 1) & 1],
                wt + (size_t)(l + 1) * 256 * 128, xlr);
        } else {
            k_skip_fc<<<rtiles, 256, 0, stream>>>(
                hbufb, stats_l, gn_w + l * HID, gn_b + l * HID, gn_ms + l * HID,
                st, skip_b, xbufs[l & 1], fc_W, fc_b, out);
        }
    }
}

// Round 11
// 434.900 us; speedup vs baseline: 1.0518x; 1.0518x over previous
//
#include <hip/hip_runtime.h>
#include <hip/hip_bf16.h>

#define NN 50000
#define EE 800000
#define NE 850000       // edges + self-loops
#define HID 128
#define NEG_SLOPE 0.2f
#define EPSN 1e-5f
#define NB 196          // buckets of 256 nodes
#define BCAP 6144       // bucket capacity (expected 4352 +- 64)
#define TB 4096         // edges per k_bin block
#define REP 32          // GraphNorm stats replicas (per-layer region)
#define NPB 8           // nodes per k_gat_node block (4 per wave, 2 waves)
#define GCAP 512        // staged csr offsets per gat block (mean 136)
#define LOG2E 1.4426950408889634f

typedef __attribute__((ext_vector_type(8))) short bf16x8;
typedef __attribute__((ext_vector_type(4))) float f32x4;
typedef __attribute__((ext_vector_type(2))) float f32x2;

__device__ __forceinline__ unsigned short f2b(float f) {
    unsigned u = __float_as_uint(f);
    unsigned r = (u + 0x7FFFu + ((u >> 16) & 1u)) >> 16;
    return (unsigned short)r;
}
__device__ __forceinline__ float b2f(unsigned short u) {
    return __uint_as_float(((unsigned)u) << 16);
}
__device__ __forceinline__ float2 up2(unsigned u) {
    return make_float2(__uint_as_float(u << 16),
                       __uint_as_float(u & 0xFFFF0000u));
}
// packed-f32 (VOP3P) helpers — clang won't form these from scalar code
__device__ __forceinline__ f32x2 up2p(unsigned u) {
    f32x2 r;
    r[0] = __uint_as_float(u << 16);
    r[1] = __uint_as_float(u & 0xFFFF0000u);
    return r;
}
__device__ __forceinline__ f32x2 pka(f32x2 a, f32x2 b) {
    f32x2 d;
    asm("v_pk_add_f32 %0, %1, %2" : "=v"(d) : "v"(a), "v"(b));
    return d;
}
__device__ __forceinline__ f32x2 pkm(f32x2 a, f32x2 b) {
    f32x2 d;
    asm("v_pk_mul_f32 %0, %1, %2" : "=v"(d) : "v"(a), "v"(b));
    return d;
}
__device__ __forceinline__ f32x2 pkf(f32x2 a, f32x2 b, f32x2 c) {
    f32x2 d;
    asm("v_pk_fma_f32 %0, %1, %2, %3" : "=v"(d) : "v"(a), "v"(b), "v"(c));
    return d;
}
__device__ __forceinline__ f32x2 pabs2(f32x2 v) {
    f32x2 r;
    r[0] = __builtin_fabsf(v[0]);
    r[1] = __builtin_fabsf(v[1]);
    return r;
}
// quad_perm DPP add (4-lane head-group reduce)
#define QPADD(p, CTRL)                                                         \
    __int_as_float(__builtin_amdgcn_update_dpp(                                \
        __float_as_int(p), __float_as_int(p), CTRL, 0xF, 0xF, false))

// Fragment-linear weight layout: [ct][ks][quad][l16][8] — 64 lanes of a wave
// read one contiguous 1KB block per B-operand load (fully coalesced).

// ---------------- prep: W->bf16 frag-linear, x->bf16, zero bcnt + stats ------
__global__ void k_prep(const float* __restrict__ x, const float* __restrict__ Wl,
                       const float* __restrict__ Wr, const float* __restrict__ skip_W,
                       unsigned short* __restrict__ xb, unsigned short* __restrict__ wt,
                       unsigned short* __restrict__ st, int* __restrict__ bcnt,
                       float* __restrict__ stats) {
    int i = blockIdx.x * blockDim.x + threadIdx.x;
    if (i < NN * HID / 4) {
        float4 v = *(const float4*)&x[i * 4];
        ushort4 o = {f2b(v.x), f2b(v.y), f2b(v.z), f2b(v.w)};
        *(ushort4*)&xb[i * 4] = o;
    }
    if (i < NB) bcnt[i] = 0;
    if (i < 4 * REP * 256) stats[i] = 0.f;      // 4 per-layer regions
    if (i < 4 * 256 * 128) {
        int l = i >> 15, idx = i & 32767;
        int j = idx & 7;
        int l16 = (idx >> 3) & 15;
        int quad = (idx >> 7) & 3;
        int ks = (idx >> 9) & 3;
        int ct = idx >> 11;            // 0..15
        int c = ct * 16 + l16;         // output col 0..255
        int k = quad * 8 + ks * 32 + j;// input dim 0..127
        float v = (c < 128) ? Wl[l * 16384 + k * 128 + c]
                            : Wr[l * 16384 + k * 128 + (c - 128)];
        wt[i] = f2b(v);
    } else if (i < 4 * 256 * 128 + 128 * 128) {
        int idx = i - 4 * 256 * 128;   // 0..16383
        int j = idx & 7;
        int l16 = (idx >> 3) & 15;
        int quad = (idx >> 7) & 3;
        int ks = (idx >> 9) & 3;
        int ct = idx >> 11;            // 0..7
        int c = ct * 16 + l16;         // output col 0..127
        int k = quad * 8 + ks * 32 + j;
        st[idx] = f2b(skip_W[k * 128 + c]);
    }
}

// ---------------- CSR build: bucket sort ----------------
__global__ void __launch_bounds__(256) k_bin(const int* __restrict__ ei,
                                             int* __restrict__ bcnt,
                                             unsigned* __restrict__ bbuf) {
    __shared__ int hist[NB];
    __shared__ int gbase[NB];
    int t = threadIdx.x;
    for (int b = t; b < NB; b += 256) hist[b] = 0;
    __syncthreads();
    int e0 = blockIdx.x * TB;
    unsigned ent[16];
    int bkt[16];
#pragma unroll
    for (int k = 0; k < 16; k++) {
        int e = e0 + k * 256 + t;
        if (e < NE) {
            int src, dst;
            if (e < EE) { src = ei[e]; dst = ei[EE + e]; }
            else        { src = e - EE; dst = src; }
            int b = dst >> 8;
            ent[k] = ((unsigned)(dst & 255) << 17) | (unsigned)src;
            bkt[k] = b;
            atomicAdd(&hist[b], 1);
        } else bkt[k] = -1;
    }
    __syncthreads();
    for (int b = t; b < NB; b += 256) {
        int c = hist[b];
        gbase[b] = (c > 0) ? atomicAdd(&bcnt[b], c) : 0;
        hist[b] = 0;
    }
    __syncthreads();
#pragma unroll
    for (int k = 0; k < 16; k++) {
        int b = bkt[k];
        if (b >= 0) {
            int pos = gbase[b] + atomicAdd(&hist[b], 1);
            if (pos < BCAP) bbuf[(size_t)b * BCAP + pos] = ent[k];
        }
    }
}

// Per-bucket CSR with inline prefix scan; csr stores BYTE offsets (src*512).
__global__ void __launch_bounds__(256) k_bucket_csr(
    const unsigned* __restrict__ bbuf, const int* __restrict__ bcnt,
    int* __restrict__ row_ptr, int* __restrict__ csr_off) {
    __shared__ unsigned se[BCAP];
    __shared__ int pre[256];
    __shared__ int hist[256], scn[256], exs[256], cur[256];
    int b = blockIdx.x, t = threadIdx.x;
    int bv = (t < NB) ? bcnt[t] : 0;
    pre[t] = bv;
    __syncthreads();
    for (int o = 1; o < 256; o <<= 1) {
        int u = (t >= o) ? pre[t - o] : 0;
        __syncthreads();
        pre[t] += u;
        __syncthreads();
    }
    int cntb = bcnt[b];
    int base = pre[b] - cntb;          // exclusive prefix
    int cnt = min(cntb, BCAP);
    hist[t] = 0;
    cur[t] = 0;
    __syncthreads();
    for (int j = t; j < cnt; j += 256) {
        unsigned e = bbuf[(size_t)b * BCAP + j];
        se[j] = e;
        atomicAdd(&hist[e >> 17], 1);
    }
    __syncthreads();
    int v = hist[t];
    scn[t] = v;
    __syncthreads();
    for (int o = 1; o < 256; o <<= 1) {
        int u = (t >= o) ? scn[t - o] : 0;
        __syncthreads();
        scn[t] += u;
        __syncthreads();
    }
    int ex = scn[t] - v;
    exs[t] = ex;
    int node = b * 256 + t;
    if (node < NN) row_ptr[node] = base + ex;
    if (b == NB - 1 && t == 0) row_ptr[NN] = NE;
    __syncthreads();
    for (int j = t; j < cnt; j += 256) {
        unsigned e = se[j];
        int dl = e >> 17;
        int p = exs[dl] + atomicAdd(&cur[dl], 1);
        csr_off[base + p] = (int)((e & 0x1FFFFu) << 9);   // src * 512 bytes
    }
}

// ---------------- MFMA GEMM (layer 0 only): xlr = Xb @ Wcat ----------------
__global__ void __launch_bounds__(256) k_gemm_dual_mfma(
    const unsigned short* __restrict__ Xb, const unsigned short* __restrict__ WT,
    unsigned short* __restrict__ C) {
    int w = threadIdx.x >> 6, lane = threadIdx.x & 63;
    int quad = lane >> 4, l16 = lane & 15;
    int r0 = blockIdx.x * 64 + w * 16;
    int lrow = r0 + l16; if (lrow >= NN) lrow = NN - 1;
    const unsigned short* arow = Xb + (size_t)lrow * 128 + quad * 8;
    bf16x8 a[4];
#pragma unroll
    for (int ks = 0; ks < 4; ks++) a[ks] = *(const bf16x8*)(arow + ks * 32);
    const unsigned short* wbase = WT + quad * 128 + l16 * 8;   // frag-linear
    f32x4 acc[16];
#pragma unroll
    for (int ct = 0; ct < 16; ct++) acc[ct] = (f32x4){0, 0, 0, 0};
#pragma unroll
    for (int ct = 0; ct < 16; ct++) {
#pragma unroll
        for (int ks = 0; ks < 4; ks++) {
            bf16x8 b = *(const bf16x8*)(wbase + ct * 2048 + ks * 512);
            acc[ct] = __builtin_amdgcn_mfma_f32_16x16x32_bf16(a[ks], b, acc[ct], 0, 0, 0);
        }
    }
    int sr = r0 + quad * 4;
#pragma unroll
    for (int ct = 0; ct < 16; ct++) {
#pragma unroll
        for (int r = 0; r < 4; r++) {
            int rr = sr + r;
            if (rr < NN) C[(size_t)rr * 256 + ct * 16 + l16] = f2b(acc[ct][r]);
        }
    }
}

// ---------------- per-block GraphNorm scoff reduce (replaces k_finalize) ----
__device__ __forceinline__ void scoff_reduce(
    const float* __restrict__ stats_l, const float* __restrict__ gn_w,
    const float* __restrict__ gn_b, const float* __restrict__ gn_ms,
    int t, float* s_tot, float* s_sc) {
    float ssum = 0.f;
    const float* sp = stats_l + t;
#pragma unroll
    for (int r = 0; r < REP; r++) ssum += sp[r * 256];
    s_tot[t] = ssum;
    __syncthreads();
    if (t < 128) {
        const float invN = 1.0f / (float)NN;
        float mean = s_tot[t] * invN;
        float ex2 = s_tot[128 + t] * invN;
        float ms = gn_ms[t];
        float var = ex2 - (2.f * ms - ms * ms) * mean * mean;
        float wsc = gn_w[t] * rsqrtf(var + EPSN);
        s_sc[t] = wsc;
        s_sc[128 + t] = gn_b[t] - wsc * ms * mean;
    }
    __syncthreads();
}

// ---------------- skip-GEMM core: acc[8] = ELU(scale*h+off) @ skipW ----------------
__device__ __forceinline__ void skip_core(
    const unsigned short* __restrict__ hbufb, const float* scoff,
    const unsigned short* __restrict__ ST, int lrow, int quad, int l16,
    f32x4 (&acc)[8]) {
    const unsigned short* hrow = hbufb + (size_t)lrow * 128 + quad * 8;
    const unsigned short* stbase = ST + quad * 128 + l16 * 8;   // frag-linear
#pragma unroll
    for (int ct = 0; ct < 8; ct++) acc[ct] = (f32x4){0, 0, 0, 0};
#pragma unroll
    for (int ks = 0; ks < 4; ks++) {
        int k0 = ks * 32;
        int kc = quad * 8 + k0;
        uint4 hw = *(const uint4*)(hrow + k0);
        float2 h01 = up2(hw.x), h23 = up2(hw.y), h45 = up2(hw.z), h67 = up2(hw.w);
        float4 sc0 = *(const float4*)(scoff + kc);
        float4 sc1 = *(const float4*)(scoff + kc + 4);
        float4 of0 = *(const float4*)(scoff + 128 + kc);
        float4 of1 = *(const float4*)(scoff + 128 + kc + 4);
        float e[8];
        e[0] = fmaf(sc0.x, h01.x, of0.x); e[1] = fmaf(sc0.y, h01.y, of0.y);
        e[2] = fmaf(sc0.z, h23.x, of0.z); e[3] = fmaf(sc0.w, h23.y, of0.w);
        e[4] = fmaf(sc1.x, h45.x, of1.x); e[5] = fmaf(sc1.y, h45.y, of1.y);
        e[6] = fmaf(sc1.z, h67.x, of1.z); e[7] = fmaf(sc1.w, h67.y, of1.w);
        bf16x8 af;
#pragma unroll
        for (int j = 0; j < 8; j++) {
            float v = e[j];
            v = (v > 0.f) ? v : (__expf(v) - 1.f);
            af[j] = (short)f2b(v);
        }
#pragma unroll
        for (int ct = 0; ct < 8; ct++) {
            bf16x8 b = *(const bf16x8*)(stbase + ct * 2048 + ks * 512);
            acc[ct] = __builtin_amdgcn_mfma_f32_16x16x32_bf16(af, b, acc[ct], 0, 0, 0);
        }
    }
}

// ---------------- fused scoff + skip + next-layer dual GEMM ----------------
__global__ void __launch_bounds__(256) k_skip_dual(
    const unsigned short* __restrict__ hbufb, const float* __restrict__ stats_l,
    const float* __restrict__ gn_w, const float* __restrict__ gn_b,
    const float* __restrict__ gn_ms,
    const unsigned short* __restrict__ ST, const float* __restrict__ skip_b,
    unsigned short* __restrict__ Xb16,
    const unsigned short* __restrict__ WTnext, unsigned short* __restrict__ xlr) {
    __shared__ unsigned short tileX[64][136];      // block-wide new X (bf16)
    __shared__ unsigned short tileC[4][16][264];   // per-wave xlr staging
    __shared__ __align__(16) float s_tot[256];
    __shared__ __align__(16) float s_sc[256];
    int t = threadIdx.x;
    int w = t >> 6, lane = t & 63;
    int quad = lane >> 4, l16 = lane & 15;
    int r0b = blockIdx.x * 64;
    int r0 = r0b + w * 16;
    int lrow = r0 + l16; if (lrow >= NN) lrow = NN - 1;
#pragma unroll
    for (int it = 0; it < 4; it++) {
        int idx = it * 256 + t;
        int row = idx >> 4;
        int c8 = (idx & 15) * 8;
        int rr = r0b + row;
        uint4 v = (rr < NN) ? *(const uint4*)&Xb16[(size_t)rr * 128 + c8]
                            : (uint4){0, 0, 0, 0};
        *(uint4*)&tileX[row][c8] = v;
    }
    scoff_reduce(stats_l, gn_w, gn_b, gn_ms, t, s_tot, s_sc);
    f32x4 acc[8];
    skip_core(hbufb, s_sc, ST, lrow, quad, l16, acc);
    __syncthreads();
#pragma unroll
    for (int ct = 0; ct < 8; ct++) {
        int c = ct * 16 + l16;
        float sb = skip_b[c];
#pragma unroll
        for (int r = 0; r < 4; r++) {
            int wrow = w * 16 + quad * 4 + r;
            float v = b2f(tileX[wrow][c]) + acc[ct][r] + sb;
            tileX[wrow][c] = f2b(v);
        }
    }
    __syncthreads();
#pragma unroll
    for (int it = 0; it < 4; it++) {
        int idx = it * 256 + t;
        int row = idx >> 4;
        int c8 = (idx & 15) * 8;
        int rr = r0b + row;
        if (rr < NN) *(uint4*)&Xb16[(size_t)rr * 128 + c8] = *(const uint4*)&tileX[row][c8];
    }
    int wrowA = w * 16 + l16;
    bf16x8 a[4];
#pragma unroll
    for (int ks = 0; ks < 4; ks++)
        a[ks] = *(const bf16x8*)&tileX[wrowA][quad * 8 + ks * 32];
    const unsigned short* wbase = WTnext + quad * 128 + l16 * 8;   // frag-linear
    f32x4 dacc[16];
#pragma unroll
    for (int ct = 0; ct < 16; ct++) dacc[ct] = (f32x4){0, 0, 0, 0};
#pragma unroll
    for (int ct = 0; ct < 16; ct++) {
#pragma unroll
        for (int ks = 0; ks < 4; ks++) {
            bf16x8 b = *(const bf16x8*)(wbase + ct * 2048 + ks * 512);
            dacc[ct] = __builtin_amdgcn_mfma_f32_16x16x32_bf16(a[ks], b, dacc[ct], 0, 0, 0);
        }
    }
#pragma unroll
    for (int ct = 0; ct < 16; ct++) {
#pragma unroll
        for (int r = 0; r < 4; r++)
            tileC[w][quad * 4 + r][ct * 16 + l16] = f2b(dacc[ct][r]);
    }
    __syncthreads();
#pragma unroll
    for (int it = 0; it < 8; it++) {
        int idx = it * 64 + lane;
        int row = idx >> 5;
        int c8 = (idx & 31) * 8;
        int rr = r0 + row;
        if (rr < NN) *(uint4*)&xlr[(size_t)rr * 256 + c8] = *(const uint4*)&tileC[w][row][c8];
    }
}

// ---------------- fused scoff + skip + final fc (last layer) ----------------
__global__ void __launch_bounds__(256) k_skip_fc(
    const unsigned short* __restrict__ hbufb, const float* __restrict__ stats_l,
    const float* __restrict__ gn_w, const float* __restrict__ gn_b,
    const float* __restrict__ gn_ms,
    const unsigned short* __restrict__ ST, const float* __restrict__ skip_b,
    const unsigned short* __restrict__ Xb16,
    const float* __restrict__ fc_W, const float* __restrict__ fc_b,
    float* __restrict__ out) {
    __shared__ unsigned short tileX[64][136];
    __shared__ __align__(16) float s_tot[256];
    __shared__ __align__(16) float s_sc[256];
    int t = threadIdx.x;
    int w = t >> 6, lane = t & 63;
    int quad = lane >> 4, l16 = lane & 15;
    int r0b = blockIdx.x * 64;
    int r0 = r0b + w * 16;
    int lrow = r0 + l16; if (lrow >= NN) lrow = NN - 1;
#pragma unroll
    for (int it = 0; it < 4; it++) {
        int idx = it * 256 + t;
        int row = idx >> 4;
        int c8 = (idx & 15) * 8;
        int rr = r0b + row;
        uint4 v = (rr < NN) ? *(const uint4*)&Xb16[(size_t)rr * 128 + c8]
                            : (uint4){0, 0, 0, 0};
        *(uint4*)&tileX[row][c8] = v;
    }
    scoff_reduce(stats_l, gn_w, gn_b, gn_ms, t, s_tot, s_sc);
    f32x4 acc[8];
    skip_core(hbufb, s_sc, ST, lrow, quad, l16, acc);
    __syncthreads();
    float p[4] = {0.f, 0.f, 0.f, 0.f};
#pragma unroll
    for (int ct = 0; ct < 8; ct++) {
        int c = ct * 16 + l16;
        float sb = skip_b[c];
        float fw = fc_W[c];
#pragma unroll
        for (int r = 0; r < 4; r++) {
            int wrow = w * 16 + quad * 4 + r;
            float v = b2f(tileX[wrow][c]) + acc[ct][r] + sb;
            p[r] = fmaf(v, fw, p[r]);
        }
    }
#pragma unroll
    for (int r = 0; r < 4; r++) {
        p[r] += __shfl_xor(p[r], 1);
        p[r] += __shfl_xor(p[r], 2);
        p[r] += __shfl_xor(p[r], 4);
        p[r] += __shfl_xor(p[r], 8);
    }
    if (l16 == 0) {
        float fb = fc_b[0];
#pragma unroll
        for (int r = 0; r < 4; r++) {
            int rr = r0 + quad * 4 + r;
            if (rr < NN) out[rr] = p[r] + fb;
        }
    }
}

// ---------------- GAT edge step ----------------
__device__ __forceinline__ void proc_edge(
    const uint4& xw, const f32x2* xr2, const f32x2* at06, const f32x2* at04,
    float& den, f32x2* acc) {
    f32x2 f0 = up2p(xw.x), f1 = up2p(xw.y);
    f32x2 f2v = up2p(xw.z), f3 = up2p(xw.w);
    f32x2 s0 = pka(f0, xr2[0]);
    f32x2 s1 = pka(f1, xr2[1]);
    f32x2 s2 = pka(f2v, xr2[2]);
    f32x2 s3 = pka(f3, xr2[3]);
    // two 4-deep chains instead of one 8-deep
    f32x2 ps1 = pkm(at06[0], s0);
    ps1 = pkf(at04[0], pabs2(s0), ps1);
    ps1 = pkf(at06[1], s1, ps1);
    ps1 = pkf(at04[1], pabs2(s1), ps1);
    f32x2 ps2 = pkm(at06[2], s2);
    ps2 = pkf(at04[2], pabs2(s2), ps2);
    ps2 = pkf(at06[3], s3, ps2);
    ps2 = pkf(at04[3], pabs2(s3), ps2);
    float p = (ps1[0] + ps2[0]) + (ps1[1] + ps2[1]);
    p += QPADD(p, 0xB1);     // xor 1 within quad (head group)
    p += QPADD(p, 0x4E);     // xor 2 within quad
    float w = exp2f(p);
    den += w;
    f32x2 w2; w2[0] = w; w2[1] = w;
    acc[0] = pkf(w2, f0, acc[0]);
    acc[1] = pkf(w2, f1, acc[1]);
    acc[2] = pkf(w2, f2v, acc[2]);
    acc[3] = pkf(w2, f3, acc[3]);
}

// ---------------- fused GATv2: R7 proven structure (48 VGPR, 53 us floor) ----
// 128 threads = 2 waves; each wave owns 4 nodes (4 slots x 16 lanes; slot g
// takes edges == g mod 4). While-loop with register rotation (compiler movs
// are cheaper than the VGPRs an unroll burns — R6/R8 evidence). Prefetch
// depth 4. Cross-slot reduce = in-wave butterfly; zero barriers in the main
// loop; LDS = 2KB.
__global__ void __launch_bounds__(128) k_gat_node(
    const unsigned short* __restrict__ xlr,
    const float* __restrict__ att, const float* __restrict__ conv_b,
    const int* __restrict__ row_ptr, const int* __restrict__ csr_off,
    unsigned short* __restrict__ houtb, float* __restrict__ stats_l) {
    __shared__ int s_off[GCAP];
    int t = threadIdx.x;
    int wv = t >> 6, lane = t & 63;
    int g = lane >> 4;       // slot 0..3 (within wave)
    int l = lane & 15;       // lane in slot: owns channels 8l..8l+7
    int i0 = blockIdx.x * NPB;
    int e0 = row_ptr[i0];
    int cnt = row_ptr[i0 + NPB] - e0;
    int stged = min(cnt, GCAP);
    for (int k = t; k < stged; k += 128) s_off[k] = csr_off[e0 + k];
    int n0 = i0 + wv * 4;    // this wave's first node
    int rp[5];
#pragma unroll
    for (int k = 0; k <= 4; k++) rp[k] = row_ptr[n0 + k];
    __syncthreads();

    const char* xbytes = (const char*)xlr;
    int lofs = 16 * l;
    f32x2 at06[4], at04[4];
    {
        float4 a0 = *(const float4*)&att[8 * l];
        float4 a1 = *(const float4*)&att[8 * l + 4];
        const float c6 = 0.6f * LOG2E, c4 = 0.4f * LOG2E;
        at06[0][0] = a0.x * c6; at06[0][1] = a0.y * c6;
        at06[1][0] = a0.z * c6; at06[1][1] = a0.w * c6;
        at06[2][0] = a1.x * c6; at06[2][1] = a1.y * c6;
        at06[3][0] = a1.z * c6; at06[3][1] = a1.w * c6;
        at04[0][0] = a0.x * c4; at04[0][1] = a0.y * c4;
        at04[1][0] = a0.z * c4; at04[1][1] = a0.w * c4;
        at04[2][0] = a1.x * c4; at04[2][1] = a1.y * c4;
        at04[3][0] = a1.z * c4; at04[3][1] = a1.w * c4;
    }
    int c0p = 8 * l + 2 * g;               // post-butterfly channel pair
    float2 cbp = *(const float2*)&conv_b[c0p];
    float saA = 0.f, sqA = 0.f, saB = 0.f, sqB = 0.f;

    // prologue: node 0 head state (depth-4: 3 heads in flight)
    uint4 xr_raw = *(const uint4*)(xbytes + (size_t)n0 * 512 + 256 + lofs);
    int start = rp[0] - e0, end = rp[1] - e0;
    int j = start + g;
    bool v0 = j < end;
    bool v1 = (j + 4) < end;
    bool v2 = (j + 8) < end;
    uint4 xw0 = {0, 0, 0, 0}, xw1 = {0, 0, 0, 0}, xw2 = {0, 0, 0, 0};
    if (v0) { int o = (j < stged) ? s_off[j] : csr_off[e0 + j];
              xw0 = *(const uint4*)(xbytes + (size_t)(unsigned)o + lofs); }
    if (v1) { int o = (j + 4 < stged) ? s_off[j + 4] : csr_off[e0 + j + 4];
              xw1 = *(const uint4*)(xbytes + (size_t)(unsigned)o + lofs); }
    if (v2) { int o = (j + 8 < stged) ? s_off[j + 8] : csr_off[e0 + j + 8];
              xw2 = *(const uint4*)(xbytes + (size_t)(unsigned)o + lofs); }

    for (int nn = 0; nn < 4; nn++) {
        f32x2 xr2[4];
        xr2[0] = up2p(xr_raw.x); xr2[1] = up2p(xr_raw.y);
        xr2[2] = up2p(xr_raw.z); xr2[3] = up2p(xr_raw.w);
        float den = 0.f;
        f32x2 acc[4];
#pragma unroll
        for (int k = 0; k < 4; k++) { acc[k][0] = 0.f; acc[k][1] = 0.f; }
        while (v0) {
            bool v3 = (j + 12) < end;
            uint4 xw3 = {0, 0, 0, 0};
            if (v3) { int o = (j + 12 < stged) ? s_off[j + 12] : csr_off[e0 + j + 12];
                      xw3 = *(const uint4*)(xbytes + (size_t)(unsigned)o + lofs); }
            proc_edge(xw0, xr2, at06, at04, den, acc);
            j += 4;
            v0 = v1; v1 = v2; v2 = v3;
            xw0 = xw1; xw1 = xw2; xw2 = xw3;
        }
        // save reduce inputs before clobbering pipeline state
        float r0v = acc[0][0], r1v = acc[0][1], r2v = acc[1][0], r3v = acc[1][1];
        float r4v = acc[2][0], r5v = acc[2][1], r6v = acc[3][0], r7v = acc[3][1];
        float dn = den;
        // issue next node's head prefetch BEFORE the reduce (hide latency)
        if (nn < 3) {
            xr_raw = *(const uint4*)(xbytes + (size_t)(n0 + nn + 1) * 512 + 256 + lofs);
            start = rp[nn + 1] - e0; end = rp[nn + 2] - e0;
            j = start + g;
            v0 = j < end;
            v1 = (j + 4) < end;
            v2 = (j + 8) < end;
            xw0 = (uint4){0, 0, 0, 0}; xw1 = (uint4){0, 0, 0, 0};
            xw2 = (uint4){0, 0, 0, 0};
            if (v0) { int o = (j < stged) ? s_off[j] : csr_off[e0 + j];
                      xw0 = *(const uint4*)(xbytes + (size_t)(unsigned)o + lofs); }
            if (v1) { int o = (j + 4 < stged) ? s_off[j + 4] : csr_off[e0 + j + 4];
                      xw1 = *(const uint4*)(xbytes + (size_t)(unsigned)o + lofs); }
            if (v2) { int o = (j + 8 < stged) ? s_off[j + 8] : csr_off[e0 + j + 8];
                      xw2 = *(const uint4*)(xbytes + (size_t)(unsigned)o + lofs); }
        }
        // cross-slot butterfly (slots = 16-lane groups): result in ALL lanes
        r0v += __shfl_xor(r0v, 16); r0v += __shfl_xor(r0v, 32);
        r1v += __shfl_xor(r1v, 16); r1v += __shfl_xor(r1v, 32);
        r2v += __shfl_xor(r2v, 16); r2v += __shfl_xor(r2v, 32);
        r3v += __shfl_xor(r3v, 16); r3v += __shfl_xor(r3v, 32);
        r4v += __shfl_xor(r4v, 16); r4v += __shfl_xor(r4v, 32);
        r5v += __shfl_xor(r5v, 16); r5v += __shfl_xor(r5v, 32);
        r6v += __shfl_xor(r6v, 16); r6v += __shfl_xor(r6v, 32);
        r7v += __shfl_xor(r7v, 16); r7v += __shfl_xor(r7v, 32);
        dn  += __shfl_xor(dn, 16);  dn  += __shfl_xor(dn, 32);
        // slot g finalizes channel pair 8l+2g (scalar ternaries: no arrays)
        float rA = (g == 0) ? r0v : (g == 1) ? r2v : (g == 2) ? r4v : r6v;
        float rB = (g == 0) ? r1v : (g == 1) ? r3v : (g == 2) ? r5v : r7v;
        float invd = 1.0f / dn;
        float hA = fmaf(rA, invd, cbp.x);
        float hB = fmaf(rB, invd, cbp.y);
        unsigned pkv = (unsigned)f2b(hA) | ((unsigned)f2b(hB) << 16);
        *(unsigned*)&houtb[(size_t)(n0 + nn) * 128 + c0p] = pkv;
        saA += hA; sqA += hA * hA;
        saB += hB; sqB += hB * hB;
    }
    {
        float* srep = stats_l + (size_t)(blockIdx.x & (REP - 1)) * 256;
        atomicAdd(&srep[c0p], saA);
        atomicAdd(&srep[c0p + 1], saB);
        atomicAdd(&srep[128 + c0p], sqA);
        atomicAdd(&srep[128 + c0p + 1], sqB);
    }
}

extern "C" void kernel_launch(void* const* d_in, const int* in_sizes, int n_in,
                              void* d_out, int out_size, void* d_ws, size_t ws_size,
                              hipStream_t stream) {
    const float* x_in   = (const float*)d_in[0];
    const int*   ei     = (const int*)d_in[1];
    const float* Wl     = (const float*)d_in[2];
    const float* Wr     = (const float*)d_in[3];
    const float* att    = (const float*)d_in[4];
    const float* conv_b = (const float*)d_in[5];
    const float* gn_w   = (const float*)d_in[6];
    const float* gn_b   = (const float*)d_in[7];
    const float* gn_ms  = (const float*)d_in[8];
    const float* skip_W = (const float*)d_in[9];
    const float* skip_b = (const float*)d_in[10];
    const float* fc_W   = (const float*)d_in[11];
    const float* fc_b   = (const float*)d_in[12];
    float* out = (float*)d_out;

    // workspace carve
    float* ws = (float*)d_ws;
    float* stats = ws;                              // 4 * REP * 256 (per-layer)
    unsigned short* xlr   = (unsigned short*)(stats + 4 * REP * 256); // N*256 bf16
    unsigned short* b16X  = xlr + (size_t)NN * 256; // N*HID bf16 (residual stream)
    unsigned short* hbufb = b16X + NN * HID;        // N*HID bf16
    unsigned short* wt    = hbufb + NN * HID;       // 4*256*128 (frag-linear)
    unsigned short* st    = wt + 4 * 256 * 128;     // 128*128 (frag-linear)
    int* row_ptr = (int*)(st + 128 * 128);          // N+1
    int* bcnt    = row_ptr + NN + 1;                // NB
    int* csr_off = bcnt + NB;                       // NE (byte offsets)
    unsigned* bbuf = (unsigned*)(csr_off + NE);     // NB*BCAP

    k_prep<<<(NN * HID / 4 + 255) / 256, 256, 0, stream>>>(
        x_in, Wl, Wr, skip_W, b16X, wt, st, bcnt, stats);

    // CSR build via bucket sort
    k_bin<<<(NE + TB - 1) / TB, 256, 0, stream>>>(ei, bcnt, bbuf);
    k_bucket_csr<<<NB, 256, 0, stream>>>(bbuf, bcnt, row_ptr, csr_off);

    const int rtiles = (NN + 63) / 64;              // 782
    const int gat_blocks = (NN + NPB - 1) / NPB;    // 6250
    k_gemm_dual_mfma<<<rtiles, 256, 0, stream>>>(b16X, wt, xlr);
    for (int l = 0; l < 4; l++) {
        float* stats_l = stats + (size_t)l * REP * 256;
        k_gat_node<<<gat_blocks, 128, 0, stream>>>(
            xlr, att + l * HID, conv_b + l * HID, row_ptr, csr_off,
            hbufb, stats_l);
        if (l < 3) {
            k_skip_dual<<<rtiles, 256, 0, stream>>>(
                hbufb, stats_l, gn_w + l * HID, gn_b + l * HID, gn_ms + l * HID,
                st, skip_b, b16X, wt + (size_t)(l + 1) * 256 * 128, xlr);
        } else {
            k_skip_fc<<<rtiles, 256, 0, stream>>>(
                hbufb, stats_l, gn_w + l * HID, gn_b + l * HID, gn_ms + l * HID,
                st, skip_b, b16X, fc_W, fc_b, out);
        }
    }
}